// Round 10
// baseline (131.097 us; speedup 1.0000x reference)
//
#include <hip/hip_runtime.h>
#include <hip/hip_bf16.h>

#define BB 128
#define NN 512
#define IND 128
#define LD 64
#define NC 10
#define FL 4
#define ROWS (BB*NN)          // 65536
#define QTR 128               // rows/block in k_gemm/k_muflow/k_dec (4 blocks/sample)

// workspace layout (float units)
#define OFF_ACC 0                        // 8: [kl, mse, nll, acc, counter,...]
#define OFF_PCNT 8                       // 128 u32 per-sample arrival counters
#define OFF_MSES 136                     // 128 f32 per-sample mse accum (atomic)
#define OFF_RDEG 264                     // [ROWS] f32
#define OFF_VM   (OFF_RDEG + ROWS)
#define OFF_VV   (OFF_VM + ROWS)
#define OFF_ZS   (OFF_VV + ROWS)
#define OFF_ZSS  (OFF_ZS + ROWS)
#define OFF_KLP  (OFF_ZSS + ROWS)        // [512]
#define OFF_XHG  (OFF_KLP + 512)         // [BB][64] f32 (atomic accum)
#define OFF_HWT  (OFF_XHG + BB*64)       // bf16 [B][64][512] = ROWS*32 floats
#define OFF_H    (OFF_HWT + ROWS*32)     // bf16 [ROWS][64]   = ROWS*32 floats
#define OFF_GSB  (OFF_H + ROWS*32)       // bf16 [ROWS][512]  = ROWS*256 floats
#define WS_NEED ((size_t)(OFF_GSB + (size_t)ROWS*256) * 4)

typedef __attribute__((ext_vector_type(8))) short short8v;
typedef __attribute__((ext_vector_type(4))) float f32x4;

__device__ inline float wave_reduce(float v) {
    #pragma unroll
    for (int m = 32; m; m >>= 1) v += __shfl_xor(v, m, 64);
    return v;
}

__device__ inline short f2bf(float f) {
    unsigned u = __float_as_uint(f);
    u += 0x7fff + ((u >> 16) & 1);      // round-to-nearest-even
    return (short)(u >> 16);
}

__device__ inline float bf2f(short s) {
    return __uint_as_float(((unsigned)(unsigned short)s) << 16);
}

// K1: deg row sums -> rdeg(ws); zero accums/pcnt/mses/xhg; bf16 copy of gs.
// 8 rows/block, 512 thr.
__global__ __launch_bounds__(512) void k_deg(const float* __restrict__ gs,
                                             float* __restrict__ ws_f,
                                             unsigned short* __restrict__ gsb) {
    int t = threadIdx.x;
    if (blockIdx.x == 0) {
        for (int i = t; i < 264; i += 512) ws_f[i] = 0.f;      // accums+pcnt+mses
    }
    if (blockIdx.x >= 1 && blockIdx.x <= 16) {
        ws_f[OFF_XHG + (blockIdx.x - 1) * 512 + t] = 0.f;      // xhg
    }
    float* rdeg = ws_f + OFF_RDEG;
    int row = blockIdx.x * 8 + (t >> 6), lane = t & 63;
    const float4* r4 = (const float4*)(gs + (size_t)row * NN) + lane * 2;
    float4 a = r4[0], b = r4[1];
    float s = a.x + a.y + a.z + a.w + b.x + b.y + b.z + b.w;
    float sr = wave_reduce(s);
    if (lane == 0) rdeg[row] = 1.0f / sr;
    if (gsb) {
        short8v v;
        v[0] = f2bf(a.x); v[1] = f2bf(a.y); v[2] = f2bf(a.z); v[3] = f2bf(a.w);
        v[4] = f2bf(b.x); v[5] = f2bf(b.y); v[6] = f2bf(b.z); v[7] = f2bf(b.w);
        *(short8v*)(gsb + (size_t)row * NN + lane * 8) = v;
    }
}

// K2: hwT[b][l][n] = bf16( rdeg[b,n] * sum_f hs[b,n,f] * W_s[f,l] )  (R3-proven)
__global__ __launch_bounds__(256) void k_hw(const float* __restrict__ hs,
                                            const float* __restrict__ W_s,
                                            const float* __restrict__ rdeg,
                                            unsigned short* __restrict__ hwT) {
    __shared__ float sW[IND * LD];       // 32 KB
    __shared__ float shs[16 * 132];      // 16 rows padded
    __shared__ unsigned short sT[64][24];
    int t = threadIdx.x;
    for (int i = t; i < IND * LD; i += 256) sW[i] = W_s[i];
    int row0 = blockIdx.x * 16;
    for (int i = t; i < 16 * IND; i += 256)
        shs[(i >> 7) * 132 + (i & 127)] = hs[(size_t)row0 * IND + i];
    __syncthreads();
    int l = t & 63, rg = t >> 6;
    float acc[4] = {0.f, 0.f, 0.f, 0.f};
    for (int f = 0; f < IND; ++f) {
        float w = sW[f * LD + l];
        #pragma unroll
        for (int r = 0; r < 4; ++r)
            acc[r] += shs[(rg * 4 + r) * 132 + f] * w;
    }
    #pragma unroll
    for (int r = 0; r < 4; ++r) {
        int row = row0 + rg * 4 + r;
        sT[l][rg * 4 + r] = (unsigned short)f2bf(acc[r] * rdeg[row]);
    }
    __syncthreads();
    if (t < 64) {
        int b = row0 >> 9, n0 = row0 & 511;
        unsigned short* dst = hwT + ((size_t)b * 64 + t) * 512 + n0;
        short8v v0, v1;
        #pragma unroll
        for (int e = 0; e < 8; ++e) { v0[e] = (short)sT[t][e]; v1[e] = (short)sT[t][8 + e]; }
        *(short8v*)dst = v0;
        *(short8v*)(dst + 8) = v1;
    }
}

// K3: 4 blocks/sample, 512 thr. Stage hwT->LDS (swizzled); C = relu(g@hw+b_s) MFMA
// over own 128 rows -> h_ws; fused D1 (vm/vv) in-register.
template<bool BF>
__global__ __launch_bounds__(512) void k_gemm(
    const float* __restrict__ gs, const unsigned short* __restrict__ gsb,
    const unsigned short* __restrict__ hwT, const float* __restrict__ b_s,
    const float* __restrict__ W_mu, const float* __restrict__ W_lv,
    const float* __restrict__ rdeg_ws, unsigned short* __restrict__ h_ws,
    float* __restrict__ vm_ws, float* __restrict__ vv_ws)
{
    __shared__ unsigned short s_hwT[64 * 512];   // 64 KB, XOR-swizzled
    __shared__ float s_rdeg[QTR];
    const int tid = threadIdx.x, lane = tid & 63, wid = tid >> 6;
    const int b = blockIdx.x >> 2, qb = blockIdx.x & 3, rbase = qb * QTR;

    // stage hwT -> LDS with swizzle (reg-staged; 8 x 16B per thread)
    {
        const unsigned short* src = hwT + (size_t)b * 64 * 512;
        #pragma unroll
        for (int v = 0; v < 8; ++v) {
            int flat = tid * 64 + v * 8;
            int l = flat >> 9, n = flat & 511;
            short8v d = *(const short8v*)(src + flat);
            *(short8v*)((char*)s_hwT + ((l * 1024 + n * 2) ^ ((l & 7) << 4))) = d;
        }
    }
    if (tid < QTR) s_rdeg[tid] = rdeg_ws[(size_t)b * NN + rbase + tid];
    __syncthreads();

    const int cq = lane & 15, koq = lane >> 4;
    const int rowg = rbase + wid * 16 + cq;
    const unsigned short* A16 = gsb + ((size_t)b * NN + rowg) * NN + koq * 8;
    const float* A32 = gs + ((size_t)b * NN + rowg) * NN + koq * 8;
    f32x4 acc0 = {0.f,0.f,0.f,0.f}, acc1 = acc0, acc2 = acc0, acc3 = acc0;
    #pragma unroll 4
    for (int kk = 0; kk < 16; ++kk) {
        short8v bf0, bf1, bf2, bf3;
        {
            int kb = (kk * 32 + koq * 8) * 2;
            bf0 = *(const short8v*)((char*)s_hwT + ((( 0 + cq) * 1024 + kb) ^ ((( 0 + cq) & 7) << 4)));
            bf1 = *(const short8v*)((char*)s_hwT + (((16 + cq) * 1024 + kb) ^ (((16 + cq) & 7) << 4)));
            bf2 = *(const short8v*)((char*)s_hwT + (((32 + cq) * 1024 + kb) ^ (((32 + cq) & 7) << 4)));
            bf3 = *(const short8v*)((char*)s_hwT + (((48 + cq) * 1024 + kb) ^ (((48 + cq) & 7) << 4)));
        }
        short8v a;
        if constexpr (BF) {
            a = *(const short8v*)(A16 + kk * 32);
        } else {
            const float4* gp = (const float4*)(A32 + kk * 32);
            float4 g0 = gp[0], g1 = gp[1];
            a[0] = f2bf(g0.x); a[1] = f2bf(g0.y); a[2] = f2bf(g0.z); a[3] = f2bf(g0.w);
            a[4] = f2bf(g1.x); a[5] = f2bf(g1.y); a[6] = f2bf(g1.z); a[7] = f2bf(g1.w);
        }
        acc0 = __builtin_amdgcn_mfma_f32_16x16x32_bf16(a, bf0, acc0, 0, 0, 0);
        acc1 = __builtin_amdgcn_mfma_f32_16x16x32_bf16(a, bf1, acc1, 0, 0, 0);
        acc2 = __builtin_amdgcn_mfma_f32_16x16x32_bf16(a, bf2, acc2, 0, 0, 0);
        acc3 = __builtin_amdgcn_mfma_f32_16x16x32_bf16(a, bf3, acc3, 0, 0, 0);
    }

    // epilogue: h -> h_ws (bf16) + fused D1 (R2-proven 16-lane shfl reduce)
    const int r0 = koq * 4;
    float bs0 = b_s[cq], bs1 = b_s[16 + cq], bs2 = b_s[32 + cq], bs3 = b_s[48 + cq];
    float wm0 = W_mu[cq], wm1 = W_mu[16 + cq], wm2 = W_mu[32 + cq], wm3 = W_mu[48 + cq];
    float wv0 = W_lv[cq], wv1 = W_lv[16 + cq], wv2 = W_lv[32 + cq], wv3 = W_lv[48 + cq];
    #pragma unroll
    for (int q = 0; q < 4; ++q) {
        int rowl = wid * 16 + r0 + q;
        int rg = rbase + rowl;
        float h0 = fmaxf(acc0[q] + bs0, 0.f);
        float h1 = fmaxf(acc1[q] + bs1, 0.f);
        float h2 = fmaxf(acc2[q] + bs2, 0.f);
        float h3 = fmaxf(acc3[q] + bs3, 0.f);
        unsigned short* hb = h_ws + ((size_t)b * NN + rg) * 64;
        hb[ 0 + cq] = (unsigned short)f2bf(h0);
        hb[16 + cq] = (unsigned short)f2bf(h1);
        hb[32 + cq] = (unsigned short)f2bf(h2);
        hb[48 + cq] = (unsigned short)f2bf(h3);
        float pm = h0 * wm0 + h1 * wm1 + h2 * wm2 + h3 * wm3;
        float pv = h0 * wv0 + h1 * wv1 + h2 * wv2 + h3 * wv3;
        #pragma unroll
        for (int mk = 8; mk; mk >>= 1) {
            pm += __shfl_xor(pm, mk, 64);
            pv += __shfl_xor(pv, mk, 64);
        }
        if (cq == 0) {
            float rd = s_rdeg[rowl];
            vm_ws[(size_t)b * NN + rg] = pm * rd;
            vv_ws[(size_t)b * NN + rg] = pv * rd;
        }
    }
}

// K4: mu/lv matvec via MFMA (B cols: 0=vm, 1=vv) + flow. (R9-proven)
template<bool BF>
__global__ __launch_bounds__(512) void k_muflow(
    const float* __restrict__ gs, const unsigned short* __restrict__ gsb,
    const float* __restrict__ vm_ws, const float* __restrict__ vv_ws,
    const float* __restrict__ eps, const float* __restrict__ b_mu,
    const float* __restrict__ b_lv, const float* __restrict__ beta,
    const float* __restrict__ fw, const float* __restrict__ fb,
    const float* __restrict__ fs, const float* __restrict__ rdeg_ws,
    float* __restrict__ zs_ws, float* __restrict__ zss_ws,
    float* __restrict__ klp)
{
    __shared__ unsigned short s_bmu[NN], s_blv[NN];
    __shared__ float s_mp[QTR], s_lp[QTR];
    __shared__ float s_fin[8];
    const int tid = threadIdx.x, lane = tid & 63, wid = tid >> 6;
    const int b = blockIdx.x >> 2, qb = blockIdx.x & 3, rbase = qb * QTR;

    if (tid < NN) {
        s_bmu[tid] = (unsigned short)f2bf(vm_ws[(size_t)b * NN + tid]);
        s_blv[tid] = (unsigned short)f2bf(vv_ws[(size_t)b * NN + tid]);
    }
    __syncthreads();

    const int cq = lane & 15, koq = lane >> 4;
    const int rowg = rbase + wid * 16 + cq;
    const unsigned short* A16 = gsb + ((size_t)b * NN + rowg) * NN + koq * 8;
    const float* A32 = gs + ((size_t)b * NN + rowg) * NN + koq * 8;
    const char* bptr = (cq == 1) ? (const char*)s_blv : (const char*)s_bmu;
    f32x4 acc = {0.f, 0.f, 0.f, 0.f};
    const short8v bz = {0, 0, 0, 0, 0, 0, 0, 0};
    #pragma unroll 4
    for (int kk = 0; kk < 16; ++kk) {
        short8v a;
        if constexpr (BF) {
            a = *(const short8v*)(A16 + kk * 32);
        } else {
            const float4* gp = (const float4*)(A32 + kk * 32);
            float4 g0 = gp[0], g1 = gp[1];
            a[0] = f2bf(g0.x); a[1] = f2bf(g0.y); a[2] = f2bf(g0.z); a[3] = f2bf(g0.w);
            a[4] = f2bf(g1.x); a[5] = f2bf(g1.y); a[6] = f2bf(g1.z); a[7] = f2bf(g1.w);
        }
        short8v bl = *(const short8v*)(bptr + (kk * 32 + koq * 8) * 2);
        short8v bfrag = (cq < 2) ? bl : bz;
        acc = __builtin_amdgcn_mfma_f32_16x16x32_bf16(a, bfrag, acc, 0, 0, 0);
    }
    int r0 = (lane >> 4) * 4;
    if (cq == 0) {
        #pragma unroll
        for (int q2 = 0; q2 < 4; ++q2) s_mp[wid * 16 + r0 + q2] = acc[q2];
    } else if (cq == 1) {
        #pragma unroll
        for (int q2 = 0; q2 < 4; ++q2) s_lp[wid * 16 + r0 + q2] = acc[q2];
    }
    __syncthreads();

    float my_kl = 0.f;
    if (tid < QTR) {
        int rg = rbase + tid;
        float mu = fmaxf(s_mp[tid] + b_mu[0], 0.f);
        float lv = fmaxf(s_lp[tid] + b_lv[0], 0.f);
        float sigma = expf(0.5f * lv);
        float z0 = eps[(size_t)b * NN + rg] * sigma + mu;
        float z = z0, lj = 0.f;
        #pragma unroll
        for (int k = 0; k < FL; ++k) {
            float tt = tanhf(fw[k] * z + fb[k]);
            float det = 1.f + fs[k] * fw[k] * (1.f - tt * tt);
            lj += logf(fabsf(det) + 1e-7f);
            z += fs[k] * tt;
        }
        float e0 = (z0 - mu) / sigma;
        float logq = -0.5f * e0 * e0 - logf(2.5f * sigma);
        float logp = -0.5f * z * z - logf(2.5f);
        my_kl = logq - lj - logp;
        float zv = 1.f / (1.f + expf(-beta[0] * z));
        float rd = rdeg_ws[(size_t)b * NN + rg];
        zs_ws[(size_t)b * NN + rg] = zv;
        zss_ws[(size_t)b * NN + rg] = zv * rd;
    }
    float kv = wave_reduce(my_kl);
    if (lane == 0) s_fin[wid] = kv;
    __syncthreads();
    if (tid == 0) {
        float ks = 0.f;
        #pragma unroll
        for (int w = 0; w < 8; ++w) ks += s_fin[w];
        klp[blockIdx.x] = ks;
    }
}

// K5: dec matvec via MFMA + mse/hg epilogue + per-sample last-block classifier
// + global finalize. 4 blocks/sample, 512 thr.
template<bool BF>
__global__ __launch_bounds__(512) void k_dec(
    const float* __restrict__ gs, const unsigned short* __restrict__ gsb,
    const float* __restrict__ zss_ws, const float* __restrict__ zs_ws,
    const unsigned short* __restrict__ h_ws, const float* __restrict__ W_dec,
    const float* __restrict__ b_dec, const float* __restrict__ klp,
    const float* __restrict__ W1, const float* __restrict__ b1,
    const float* __restrict__ W2, const float* __restrict__ b2,
    const int* __restrict__ labels, float* __restrict__ ws_f,
    float* __restrict__ out)
{
    __shared__ unsigned short s_bz[NN];
    __shared__ float s_zs[QTR];
    __shared__ float s_dp[QTR];
    __shared__ float s_red[8 * 68];
    __shared__ float s_fin[8];
    __shared__ float s_hg[64], s_x[64], s_lg[12];
    __shared__ int s_win;
    const int tid = threadIdx.x, lane = tid & 63, wid = tid >> 6;
    const int b = blockIdx.x >> 2, qb = blockIdx.x & 3, rbase = qb * QTR;

    float* accums = ws_f + OFF_ACC;
    unsigned* pcnt = (unsigned*)(ws_f + OFF_PCNT);
    float* mses = ws_f + OFF_MSES;
    float* xhg = ws_f + OFF_XHG;

    if (tid < NN) s_bz[tid] = (unsigned short)f2bf(zss_ws[(size_t)b * NN + tid]);
    if (tid < QTR) s_zs[tid] = zs_ws[(size_t)b * NN + rbase + tid];
    __syncthreads();

    const int cq = lane & 15, koq = lane >> 4;
    const int rowg = rbase + wid * 16 + cq;
    const unsigned short* A16 = gsb + ((size_t)b * NN + rowg) * NN + koq * 8;
    const float* A32 = gs + ((size_t)b * NN + rowg) * NN + koq * 8;
    f32x4 acc = {0.f, 0.f, 0.f, 0.f};
    const short8v bz = {0, 0, 0, 0, 0, 0, 0, 0};
    #pragma unroll 4
    for (int kk = 0; kk < 16; ++kk) {
        short8v a;
        if constexpr (BF) {
            a = *(const short8v*)(A16 + kk * 32);
        } else {
            const float4* gp = (const float4*)(A32 + kk * 32);
            float4 g0 = gp[0], g1 = gp[1];
            a[0] = f2bf(g0.x); a[1] = f2bf(g0.y); a[2] = f2bf(g0.z); a[3] = f2bf(g0.w);
            a[4] = f2bf(g1.x); a[5] = f2bf(g1.y); a[6] = f2bf(g1.z); a[7] = f2bf(g1.w);
        }
        short8v bl = *(const short8v*)((const char*)s_bz + (kk * 32 + koq * 8) * 2);
        short8v bfrag = (cq == 0) ? bl : bz;
        acc = __builtin_amdgcn_mfma_f32_16x16x32_bf16(a, bfrag, acc, 0, 0, 0);
    }
    int r0 = (lane >> 4) * 4;
    if (cq == 0) {
        #pragma unroll
        for (int q2 = 0; q2 < 4; ++q2) s_dp[wid * 16 + r0 + q2] = acc[q2];
    }
    __syncthreads();

    float wd = W_dec[lane], bd = b_dec[lane];
    float msacc = 0.f, hgacc = 0.f;
    #pragma unroll 4
    for (int r = 0; r < 16; ++r) {
        int rl = wid * 16 + r, rg = rbase + rl;
        float dval = fmaxf(s_dp[rl] * wd + bd, 0.f);
        float hval = bf2f((short)h_ws[((size_t)b * NN + rg) * 64 + lane]);
        float diff = hval - dval;
        msacc += diff * diff;
        hgacc += hval * s_zs[rl];
    }
    s_red[wid * 68 + lane] = hgacc;
    float mv = wave_reduce(msacc);
    if (lane == 0) s_fin[wid] = mv;
    __syncthreads();
    if (tid == 0) {
        float ms = 0.f;
        #pragma unroll
        for (int w = 0; w < 8; ++w) ms += s_fin[w];
        atomicAdd(&mses[b], ms);
    }
    if (wid == 0) {
        float hgv = 0.f;
        #pragma unroll
        for (int w = 0; w < 8; ++w) hgv += s_red[w * 68 + lane];
        atomicAdd(&xhg[(size_t)b * 64 + lane], hgv);
    }
    __syncthreads();            // drains all outstanding atomics (vmcnt(0) before barrier)
    if (tid == 0) s_win = (atomicAdd(&pcnt[b], 1u) == 3u) ? 1 : 0;
    __syncthreads();

    if (s_win && wid == 0) {
        // coherent reads of sibling contributions via atomic RMW
        float hg = atomicAdd(&xhg[(size_t)b * 64 + lane], 0.f);
        s_hg[lane] = hg;
        float x = b1[lane];
        #pragma unroll 8
        for (int k = 0; k < LD; ++k) x += s_hg[k] * W1[k * LD + lane];
        s_x[lane] = fmaxf(x, 0.f);
        if (lane < NC) {
            float lg = b2[lane];
            #pragma unroll 8
            for (int k = 0; k < LD; ++k) lg += s_x[k] * W2[k * NC + lane];
            s_lg[lane] = lg;
        }
        if (lane == 0) {
            float mx = s_lg[0]; int pred = 0;
            #pragma unroll
            for (int c = 1; c < NC; ++c) if (s_lg[c] > mx) { mx = s_lg[c]; pred = c; }
            float se = 0.f;
            #pragma unroll
            for (int c = 0; c < NC; ++c) se += expf(s_lg[c] - mx);
            int lab = labels[b];
            float nll = -(s_lg[lab] - (mx + logf(se)));
            float kl4 = klp[4*b] + klp[4*b+1] + klp[4*b+2] + klp[4*b+3];
            float msS = atomicAdd(&mses[b], 0.f);
            atomicAdd(&accums[0], kl4);
            atomicAdd(&accums[1], msS);
            atomicAdd(&accums[2], nll);
            if (pred == lab) atomicAdd(&accums[3], 1.0f);
            __threadfence();
            unsigned old = atomicAdd((unsigned*)&accums[4], 1u);
            if (old == BB - 1) {
                float kk = atomicAdd(&accums[0], 0.f);
                float mm = atomicAdd(&accums[1], 0.f);
                float nn = atomicAdd(&accums[2], 0.f);
                float aa = atomicAdd(&accums[3], 0.f);
                out[0] = nn / (float)BB
                       + mm / ((float)BB * NN * LD)
                       + kk / ((float)BB * NN);
                out[1] = aa / (float)BB;
            }
        }
    }
}

extern "C" void kernel_launch(void* const* d_in, const int* in_sizes, int n_in,
                              void* d_out, int out_size, void* d_ws, size_t ws_size,
                              hipStream_t stream) {
    const float* gs    = (const float*)d_in[0];
    const float* hs    = (const float*)d_in[1];
    const int*   labels= (const int*)d_in[2];
    const float* eps   = (const float*)d_in[3];
    const float* W_s   = (const float*)d_in[4];
    const float* b_s   = (const float*)d_in[5];
    const float* W_mu  = (const float*)d_in[6];
    const float* b_mu  = (const float*)d_in[7];
    const float* W_lv  = (const float*)d_in[8];
    const float* b_lv  = (const float*)d_in[9];
    const float* W_dec = (const float*)d_in[10];
    const float* b_dec = (const float*)d_in[11];
    const float* W1    = (const float*)d_in[12];
    const float* b1    = (const float*)d_in[13];
    const float* W2    = (const float*)d_in[14];
    const float* b2    = (const float*)d_in[15];
    const float* beta  = (const float*)d_in[16];
    const float* fw    = (const float*)d_in[17];
    const float* fb    = (const float*)d_in[18];
    const float* fs    = (const float*)d_in[19];

    float* ws      = (float*)d_ws;
    float* rdeg    = ws + OFF_RDEG;
    float* vm_ws   = ws + OFF_VM;
    float* vv_ws   = ws + OFF_VV;
    float* zs_ws   = ws + OFF_ZS;
    float* zss_ws  = ws + OFF_ZSS;
    float* klp     = ws + OFF_KLP;
    unsigned short* hwT  = (unsigned short*)(ws + OFF_HWT);
    unsigned short* h_ws = (unsigned short*)(ws + OFF_H);
    unsigned short* gsb  = (unsigned short*)(ws + OFF_GSB);
    float* out = (float*)d_out;

    bool big = ws_size >= WS_NEED;

    k_deg<<<ROWS / 8, 512, 0, stream>>>(gs, ws, big ? gsb : nullptr);
    k_hw<<<ROWS / 16, 256, 0, stream>>>(hs, W_s, rdeg, hwT);
    if (big) {
        k_gemm<true><<<4 * BB, 512, 0, stream>>>(gs, gsb, hwT, b_s, W_mu, W_lv,
                                                 rdeg, h_ws, vm_ws, vv_ws);
        k_muflow<true><<<4 * BB, 512, 0, stream>>>(gs, gsb, vm_ws, vv_ws, eps, b_mu, b_lv,
                                                   beta, fw, fb, fs, rdeg, zs_ws, zss_ws,
                                                   klp);
        k_dec<true><<<4 * BB, 512, 0, stream>>>(gs, gsb, zss_ws, zs_ws, h_ws, W_dec, b_dec,
                                                klp, W1, b1, W2, b2, labels, ws, out);
    } else {
        k_gemm<false><<<4 * BB, 512, 0, stream>>>(gs, gsb, hwT, b_s, W_mu, W_lv,
                                                  rdeg, h_ws, vm_ws, vv_ws);
        k_muflow<false><<<4 * BB, 512, 0, stream>>>(gs, gsb, vm_ws, vv_ws, eps, b_mu, b_lv,
                                                    beta, fw, fb, fs, rdeg, zs_ws, zss_ws,
                                                    klp);
        k_dec<false><<<4 * BB, 512, 0, stream>>>(gs, gsb, zss_ws, zs_ws, h_ws, W_dec, b_dec,
                                                 klp, W1, b1, W2, b2, labels, ws, out);
    }
}

// Round 11
// 102.376 us; speedup vs baseline: 1.2805x; 1.2805x over previous
//
#include <hip/hip_runtime.h>
#include <hip/hip_bf16.h>

#define BB 128
#define NN 512
#define IND 128
#define LD 64
#define NC 10
#define FL 4
#define ROWS (BB*NN)          // 65536
#define HALF 256              // rows/block in k_hwgemm (2 blocks/sample)
#define QTR 128               // rows/block in k_muflow/k_dec (4 blocks/sample)

// workspace layout (float units)
#define OFF_ACC 0                        // 8: [kl, mse, nll, acc, counter,...]
#define OFF_RDEG (OFF_ACC + 8)           // [ROWS] f32
#define OFF_VM   (OFF_RDEG + ROWS)
#define OFF_VV   (OFF_VM + ROWS)
#define OFF_ZS   (OFF_VV + ROWS)
#define OFF_ZSS  (OFF_ZS + ROWS)
#define OFF_KLP  (OFF_ZSS + ROWS)        // [512]
#define OFF_MSEP (OFF_KLP + 512)         // [512]
#define OFF_XHG  (OFF_MSEP + 512)        // [BB][4][64] f32
#define OFF_H    (OFF_XHG + BB*256)      // bf16 [ROWS][64] = ROWS*32 floats
#define OFF_GSB  (OFF_H + ROWS*32)       // bf16 [ROWS][512] = ROWS*256 floats
#define WS_NEED ((size_t)(OFF_GSB + (size_t)ROWS*256) * 4)

typedef __attribute__((ext_vector_type(8))) short short8v;
typedef __attribute__((ext_vector_type(4))) float f32x4;

__device__ inline float wave_reduce(float v) {
    #pragma unroll
    for (int m = 32; m; m >>= 1) v += __shfl_xor(v, m, 64);
    return v;
}

__device__ inline short f2bf(float f) {
    unsigned u = __float_as_uint(f);
    u += 0x7fff + ((u >> 16) & 1);      // round-to-nearest-even
    return (short)(u >> 16);
}

__device__ inline float bf2f(short s) {
    return __uint_as_float(((unsigned)(unsigned short)s) << 16);
}

// K1: deg row sums -> rdeg(ws); zero accums; bf16 copy of gs. 4 rows/block.
__global__ __launch_bounds__(256) void k_deg(const float* __restrict__ gs,
                                             float* __restrict__ rdeg,
                                             float* __restrict__ accums,
                                             unsigned short* __restrict__ gsb) {
    if (blockIdx.x == 0 && threadIdx.x < 8) accums[threadIdx.x] = 0.f;
    int t = threadIdx.x;
    int row = blockIdx.x * 4 + (t >> 6), lane = t & 63;
    const float4* r4 = (const float4*)(gs + (size_t)row * NN) + lane * 2;
    float4 a = r4[0], b = r4[1];
    float s = a.x + a.y + a.z + a.w + b.x + b.y + b.z + b.w;
    float sr = wave_reduce(s);
    if (lane == 0) rdeg[row] = 1.0f / sr;
    if (gsb) {
        short8v v;
        v[0] = f2bf(a.x); v[1] = f2bf(a.y); v[2] = f2bf(a.z); v[3] = f2bf(a.w);
        v[4] = f2bf(b.x); v[5] = f2bf(b.y); v[6] = f2bf(b.z); v[7] = f2bf(b.w);
        *(short8v*)(gsb + (size_t)row * NN + lane * 8) = v;
    }
}

// K2: 2 blocks/sample. Full hwT (duplicated, MFMA) -> LDS; C (own 256 rows, MFMA)
// -> h(ws); D1 -> vm/vv(ws). 1024 thr = 16 waves.
template<bool BF>
__global__ __launch_bounds__(1024) void k_hwgemm(
    const float* __restrict__ gs, const unsigned short* __restrict__ gsb,
    const float* __restrict__ hs, const float* __restrict__ W_s,
    const float* __restrict__ b_s, const float* __restrict__ W_mu,
    const float* __restrict__ W_lv, const float* __restrict__ rdeg_ws,
    unsigned short* __restrict__ h_ws, float* __restrict__ vm_ws,
    float* __restrict__ vv_ws)
{
    __shared__ unsigned short s_hwT[64 * 512];   // 64 KB, XOR-swizzled
    __shared__ unsigned short s_h[HALF * 64];    // 32 KB (aliased as sWT in B)
    __shared__ float s_rdeg[NN];

    const int tid = threadIdx.x, lane = tid & 63, wid = tid >> 6;
    const int b = blockIdx.x >> 1, p = blockIdx.x & 1, rbase = p * HALF;

    if (tid < NN) s_rdeg[tid] = rdeg_ws[(size_t)b * NN + tid];

    // ---- B1: W_s^T bf16 swizzled into sWT (alias of s_h) ----
    unsigned short* sWT = s_h;
    {
        const float4* wp = (const float4*)W_s + tid * 2;
        float4 w0 = wp[0], w1 = wp[1];
        int k = tid >> 3, l0 = (tid & 7) * 8;
        float wv[8] = {w0.x, w0.y, w0.z, w0.w, w1.x, w1.y, w1.z, w1.w};
        #pragma unroll
        for (int e = 0; e < 8; ++e) {
            int l = l0 + e;
            int byte = (l * 256 + k * 2) ^ ((l & 7) << 4);
            *(unsigned short*)((char*)sWT + byte) = (unsigned short)f2bf(wv[e]);
        }
    }
    __syncthreads();

    // ---- B2: full hwT[l][n] = bf16(rdeg[n]*(hs@W_s)[n][l]) via MFMA ----
    {
        int n0 = wid * 32, cq = lane & 15, koq = lane >> 4;
        f32x4 accB[2][4] = {};
        #pragma unroll
        for (int kk = 0; kk < 4; ++kk) {
            short8v bf[4];
            #pragma unroll
            for (int lt = 0; lt < 4; ++lt) {
                int l = lt * 16 + cq;
                int byte = (l * 256 + (kk * 32 + koq * 8) * 2) ^ ((l & 7) << 4);
                bf[lt] = *(const short8v*)((char*)sWT + byte);
            }
            #pragma unroll
            for (int nt = 0; nt < 2; ++nt) {
                int row = n0 + nt * 16 + cq;
                const float4* hp = (const float4*)(hs + ((size_t)b * NN + row) * IND
                                                   + kk * 32 + koq * 8);
                float4 h0 = hp[0], h1 = hp[1];
                short8v a;
                a[0] = f2bf(h0.x); a[1] = f2bf(h0.y); a[2] = f2bf(h0.z); a[3] = f2bf(h0.w);
                a[4] = f2bf(h1.x); a[5] = f2bf(h1.y); a[6] = f2bf(h1.z); a[7] = f2bf(h1.w);
                #pragma unroll
                for (int lt = 0; lt < 4; ++lt)
                    accB[nt][lt] = __builtin_amdgcn_mfma_f32_16x16x32_bf16(a, bf[lt], accB[nt][lt], 0, 0, 0);
            }
        }
        __syncthreads();
        int r0 = (lane >> 4) * 4;
        #pragma unroll
        for (int nt = 0; nt < 2; ++nt)
            #pragma unroll
            for (int lt = 0; lt < 4; ++lt)
                #pragma unroll
                for (int q = 0; q < 4; ++q) {
                    int n = n0 + nt * 16 + r0 + q;
                    int l = lt * 16 + cq;
                    int byte = (l * 1024 + n * 2) ^ ((l & 7) << 4);
                    *(unsigned short*)((char*)s_hwT + byte) =
                        (unsigned short)f2bf(accB[nt][lt][q] * s_rdeg[n]);
                }
    }
    __syncthreads();   // full hwT ready

    // ---- C: h(own rows) = relu(g @ hw + b_s) via MFMA ----
    {
        int cq = lane & 15, koq = lane >> 4;
        int rowl = wid * 16 + cq, rowg = rbase + rowl;
        const unsigned short* A16 = gsb + ((size_t)b * NN + rowg) * NN + koq * 8;
        const float* A32 = gs + ((size_t)b * NN + rowg) * NN + koq * 8;
        f32x4 accC[4] = {};
        for (int kk = 0; kk < 16; ++kk) {
            short8v bf[4];
            #pragma unroll
            for (int lt = 0; lt < 4; ++lt) {
                int l = lt * 16 + cq;
                int byte = (l * 1024 + (kk * 32 + koq * 8) * 2) ^ ((l & 7) << 4);
                bf[lt] = *(const short8v*)((char*)s_hwT + byte);
            }
            short8v a;
            if constexpr (BF) {
                a = *(const short8v*)(A16 + kk * 32);
            } else {
                const float4* gp = (const float4*)(A32 + kk * 32);
                float4 g0 = gp[0], g1 = gp[1];
                a[0] = f2bf(g0.x); a[1] = f2bf(g0.y); a[2] = f2bf(g0.z); a[3] = f2bf(g0.w);
                a[4] = f2bf(g1.x); a[5] = f2bf(g1.y); a[6] = f2bf(g1.z); a[7] = f2bf(g1.w);
            }
            #pragma unroll
            for (int lt = 0; lt < 4; ++lt)
                accC[lt] = __builtin_amdgcn_mfma_f32_16x16x32_bf16(a, bf[lt], accC[lt], 0, 0, 0);
        }
        int r0 = (lane >> 4) * 4;
        float bsv[4];
        #pragma unroll
        for (int lt = 0; lt < 4; ++lt) bsv[lt] = b_s[lt * 16 + cq];
        #pragma unroll
        for (int lt = 0; lt < 4; ++lt)
            #pragma unroll
            for (int q = 0; q < 4; ++q) {
                int nloc = wid * 16 + r0 + q;
                int l = lt * 16 + cq;
                s_h[nloc * 64 + l] = (unsigned short)f2bf(fmaxf(accC[lt][q] + bsv[lt], 0.f));
            }
    }
    __syncthreads();

    // ---- dump h -> ws (coalesced) ----
    {
        int rowl = tid >> 2, off = (tid & 3) * 16;
        unsigned short* dst = h_ws + ((size_t)(b * NN + rbase + rowl)) * 64 + off;
        const unsigned short* src = &s_h[rowl * 64 + off];
        *(short8v*)dst = *(const short8v*)src;
        *(short8v*)(dst + 8) = *(const short8v*)(src + 8);
    }

    // ---- D1: vm/vv for own rows -> ws ----
    {
        int g16 = tid >> 4, l16 = tid & 15;
        float wmu[4], wlv[4];
        #pragma unroll
        for (int e = 0; e < 4; ++e) { wmu[e] = W_mu[l16 * 4 + e]; wlv[e] = W_lv[l16 * 4 + e]; }
        #pragma unroll
        for (int rr = 0; rr < 4; ++rr) {
            int rowl = g16 * 4 + rr;
            const unsigned short* hp = &s_h[rowl * 64 + l16 * 4];
            float pm = 0.f, pv = 0.f;
            #pragma unroll
            for (int e = 0; e < 4; ++e) {
                float hv = bf2f((short)hp[e]);
                pm += hv * wmu[e]; pv += hv * wlv[e];
            }
            #pragma unroll
            for (int m = 1; m <= 8; m <<= 1) {
                pm += __shfl_xor(pm, m, 64);
                pv += __shfl_xor(pv, m, 64);
            }
            if (l16 == 0) {
                float rd = s_rdeg[rbase + rowl];
                vm_ws[(size_t)b * NN + rbase + rowl] = pm * rd;
                vv_ws[(size_t)b * NN + rbase + rowl] = pv * rd;
            }
        }
    }
}

// K3: mu/lv matvec via MFMA (B cols: 0=vm, 1=vv, rest 0) + flow.
// 4 blocks/sample, 512 thr = 8 waves, 16 rows/wave.
template<bool BF>
__global__ __launch_bounds__(512) void k_muflow(
    const float* __restrict__ gs, const unsigned short* __restrict__ gsb,
    const float* __restrict__ vm_ws, const float* __restrict__ vv_ws,
    const float* __restrict__ eps, const float* __restrict__ b_mu,
    const float* __restrict__ b_lv, const float* __restrict__ beta,
    const float* __restrict__ fw, const float* __restrict__ fb,
    const float* __restrict__ fs, const float* __restrict__ rdeg_ws,
    float* __restrict__ zs_ws, float* __restrict__ zss_ws,
    float* __restrict__ klp)
{
    __shared__ unsigned short s_bmu[NN], s_blv[NN];
    __shared__ float s_mp[QTR], s_lp[QTR];
    __shared__ float s_fin[8];
    const int tid = threadIdx.x, lane = tid & 63, wid = tid >> 6;
    const int b = blockIdx.x >> 2, qb = blockIdx.x & 3, rbase = qb * QTR;

    if (tid < NN) {
        s_bmu[tid] = (unsigned short)f2bf(vm_ws[(size_t)b * NN + tid]);
        s_blv[tid] = (unsigned short)f2bf(vv_ws[(size_t)b * NN + tid]);
    }
    __syncthreads();

    const int cq = lane & 15, koq = lane >> 4;
    const int rowl = wid * 16 + cq, rowg = rbase + rowl;
    const unsigned short* A16 = gsb + ((size_t)b * NN + rowg) * NN + koq * 8;
    const float* A32 = gs + ((size_t)b * NN + rowg) * NN + koq * 8;
    const char* bptr = (cq == 1) ? (const char*)s_blv : (const char*)s_bmu;
    f32x4 acc = {0.f, 0.f, 0.f, 0.f};
    const short8v bz = {0, 0, 0, 0, 0, 0, 0, 0};
    #pragma unroll 4
    for (int kk = 0; kk < 16; ++kk) {
        short8v a;
        if constexpr (BF) {
            a = *(const short8v*)(A16 + kk * 32);
        } else {
            const float4* gp = (const float4*)(A32 + kk * 32);
            float4 g0 = gp[0], g1 = gp[1];
            a[0] = f2bf(g0.x); a[1] = f2bf(g0.y); a[2] = f2bf(g0.z); a[3] = f2bf(g0.w);
            a[4] = f2bf(g1.x); a[5] = f2bf(g1.y); a[6] = f2bf(g1.z); a[7] = f2bf(g1.w);
        }
        short8v bl = *(const short8v*)(bptr + (kk * 32 + koq * 8) * 2);
        short8v bfrag = (cq < 2) ? bl : bz;
        acc = __builtin_amdgcn_mfma_f32_16x16x32_bf16(a, bfrag, acc, 0, 0, 0);
    }
    int r0 = (lane >> 4) * 4;
    if (cq == 0) {
        #pragma unroll
        for (int q2 = 0; q2 < 4; ++q2) s_mp[wid * 16 + r0 + q2] = acc[q2];
    } else if (cq == 1) {
        #pragma unroll
        for (int q2 = 0; q2 < 4; ++q2) s_lp[wid * 16 + r0 + q2] = acc[q2];
    }
    __syncthreads();

    float my_kl = 0.f;
    if (tid < QTR) {
        int rg = rbase + tid;
        float mu = fmaxf(s_mp[tid] + b_mu[0], 0.f);
        float lv = fmaxf(s_lp[tid] + b_lv[0], 0.f);
        float sigma = expf(0.5f * lv);
        float z0 = eps[(size_t)b * NN + rg] * sigma + mu;
        float z = z0, lj = 0.f;
        #pragma unroll
        for (int k = 0; k < FL; ++k) {
            float tt = tanhf(fw[k] * z + fb[k]);
            float det = 1.f + fs[k] * fw[k] * (1.f - tt * tt);
            lj += logf(fabsf(det) + 1e-7f);
            z += fs[k] * tt;
        }
        float e0 = (z0 - mu) / sigma;
        float logq = -0.5f * e0 * e0 - logf(2.5f * sigma);
        float logp = -0.5f * z * z - logf(2.5f);
        my_kl = logq - lj - logp;
        float zv = 1.f / (1.f + expf(-beta[0] * z));
        float rd = rdeg_ws[(size_t)b * NN + rg];
        zs_ws[(size_t)b * NN + rg] = zv;
        zss_ws[(size_t)b * NN + rg] = zv * rd;
    }
    float kv = wave_reduce(my_kl);
    if (lane == 0) s_fin[wid] = kv;
    __syncthreads();
    if (tid == 0) {
        float ks = 0.f;
        #pragma unroll
        for (int w = 0; w < 8; ++w) ks += s_fin[w];
        klp[blockIdx.x] = ks;
    }
}

// K4: dec matvec via MFMA (B col 0 = zss) + mse/hg epilogue.
// 4 blocks/sample, 512 thr.
template<bool BF>
__global__ __launch_bounds__(512) void k_dec(
    const float* __restrict__ gs, const unsigned short* __restrict__ gsb,
    const float* __restrict__ zss_ws, const float* __restrict__ zs_ws,
    const unsigned short* __restrict__ h_ws, const float* __restrict__ W_dec,
    const float* __restrict__ b_dec, float* __restrict__ msep,
    float* __restrict__ xhg)
{
    __shared__ unsigned short s_bz[NN];
    __shared__ float s_zs[QTR];
    __shared__ float s_dp[QTR];
    __shared__ float s_red[8 * 68];
    __shared__ float s_fin[8];
    const int tid = threadIdx.x, lane = tid & 63, wid = tid >> 6;
    const int b = blockIdx.x >> 2, qb = blockIdx.x & 3, rbase = qb * QTR;

    if (tid < NN) s_bz[tid] = (unsigned short)f2bf(zss_ws[(size_t)b * NN + tid]);
    if (tid < QTR) s_zs[tid] = zs_ws[(size_t)b * NN + rbase + tid];
    __syncthreads();

    const int cq = lane & 15, koq = lane >> 4;
    const int rowl = wid * 16 + cq, rowg = rbase + rowl;
    const unsigned short* A16 = gsb + ((size_t)b * NN + rowg) * NN + koq * 8;
    const float* A32 = gs + ((size_t)b * NN + rowg) * NN + koq * 8;
    f32x4 acc = {0.f, 0.f, 0.f, 0.f};
    const short8v bz = {0, 0, 0, 0, 0, 0, 0, 0};
    #pragma unroll 4
    for (int kk = 0; kk < 16; ++kk) {
        short8v a;
        if constexpr (BF) {
            a = *(const short8v*)(A16 + kk * 32);
        } else {
            const float4* gp = (const float4*)(A32 + kk * 32);
            float4 g0 = gp[0], g1 = gp[1];
            a[0] = f2bf(g0.x); a[1] = f2bf(g0.y); a[2] = f2bf(g0.z); a[3] = f2bf(g0.w);
            a[4] = f2bf(g1.x); a[5] = f2bf(g1.y); a[6] = f2bf(g1.z); a[7] = f2bf(g1.w);
        }
        short8v bl = *(const short8v*)((const char*)s_bz + (kk * 32 + koq * 8) * 2);
        short8v bfrag = (cq == 0) ? bl : bz;
        acc = __builtin_amdgcn_mfma_f32_16x16x32_bf16(a, bfrag, acc, 0, 0, 0);
    }
    int r0 = (lane >> 4) * 4;
    if (cq == 0) {
        #pragma unroll
        for (int q2 = 0; q2 < 4; ++q2) s_dp[wid * 16 + r0 + q2] = acc[q2];
    }
    __syncthreads();

    float wd = W_dec[lane], bd = b_dec[lane];
    float msacc = 0.f, hgacc = 0.f;
    #pragma unroll 4
    for (int r = 0; r < 16; ++r) {
        int rl = wid * 16 + r, rg = rbase + rl;
        float dval = fmaxf(s_dp[rl] * wd + bd, 0.f);
        float hval = bf2f((short)h_ws[((size_t)b * NN + rg) * 64 + lane]);
        float diff = hval - dval;
        msacc += diff * diff;
        hgacc += hval * s_zs[rl];
    }
    s_red[wid * 68 + lane] = hgacc;
    float mv = wave_reduce(msacc);
    if (lane == 0) s_fin[wid] = mv;
    __syncthreads();
    if (tid == 0) {
        float ms = 0.f;
        #pragma unroll
        for (int w = 0; w < 8; ++w) ms += s_fin[w];
        msep[blockIdx.x] = ms;
    }
    if (wid == 0) {
        float hgv = 0.f;
        #pragma unroll
        for (int w = 0; w < 8; ++w) hgv += s_red[w * 68 + lane];
        xhg[(size_t)b * 256 + qb * 64 + lane] = hgv;
    }
}

// K5: classifier per sample + kl/mse partial sums + nll/acc atomics + finalize.
__global__ __launch_bounds__(64) void k_cls(const float* __restrict__ xhg,
                                            const float* __restrict__ klp,
                                            const float* __restrict__ msep,
                                            const float* __restrict__ W1,
                                            const float* __restrict__ b1,
                                            const float* __restrict__ W2,
                                            const float* __restrict__ b2,
                                            const int* __restrict__ labels,
                                            float* __restrict__ accums,
                                            float* __restrict__ out)
{
    __shared__ float s_hg[64], s_x[64], s_lg[12];
    int b = blockIdx.x, l = threadIdx.x;
    s_hg[l] = xhg[(size_t)b * 256 + l] + xhg[(size_t)b * 256 + 64 + l]
            + xhg[(size_t)b * 256 + 128 + l] + xhg[(size_t)b * 256 + 192 + l];
    if (l == 0) atomicAdd(&accums[0], klp[4*b] + klp[4*b+1] + klp[4*b+2] + klp[4*b+3]);
    if (l == 1) atomicAdd(&accums[1], msep[4*b] + msep[4*b+1] + msep[4*b+2] + msep[4*b+3]);
    __syncthreads();
    float x = b1[l];
    #pragma unroll 8
    for (int k = 0; k < LD; ++k) x += s_hg[k] * W1[k * LD + l];
    s_x[l] = fmaxf(x, 0.f);
    __syncthreads();
    if (l < NC) {
        float lg = b2[l];
        #pragma unroll 8
        for (int k = 0; k < LD; ++k) lg += s_x[k] * W2[k * NC + l];
        s_lg[l] = lg;
    }
    __syncthreads();
    if (l == 0) {
        float mx = s_lg[0]; int pred = 0;
        #pragma unroll
        for (int c = 1; c < NC; ++c) if (s_lg[c] > mx) { mx = s_lg[c]; pred = c; }
        float se = 0.f;
        #pragma unroll
        for (int c = 0; c < NC; ++c) se += expf(s_lg[c] - mx);
        int lab = labels[b];
        atomicAdd(&accums[2], -(s_lg[lab] - (mx + logf(se))));
        if (pred == lab) atomicAdd(&accums[3], 1.0f);
        __threadfence();
        unsigned old = atomicAdd((unsigned*)&accums[4], 1u);
        if (old == BB - 1) {
            float kk = atomicAdd(&accums[0], 0.f);
            float mm = atomicAdd(&accums[1], 0.f);
            float nn = atomicAdd(&accums[2], 0.f);
            float aa = atomicAdd(&accums[3], 0.f);
            out[0] = nn / (float)BB
                   + mm / ((float)BB * NN * LD)
                   + kk / ((float)BB * NN);
            out[1] = aa / (float)BB;
        }
    }
}

extern "C" void kernel_launch(void* const* d_in, const int* in_sizes, int n_in,
                              void* d_out, int out_size, void* d_ws, size_t ws_size,
                              hipStream_t stream) {
    const float* gs    = (const float*)d_in[0];
    const float* hs    = (const float*)d_in[1];
    const int*   labels= (const int*)d_in[2];
    const float* eps   = (const float*)d_in[3];
    const float* W_s   = (const float*)d_in[4];
    const float* b_s   = (const float*)d_in[5];
    const float* W_mu  = (const float*)d_in[6];
    const float* b_mu  = (const float*)d_in[7];
    const float* W_lv  = (const float*)d_in[8];
    const float* b_lv  = (const float*)d_in[9];
    const float* W_dec = (const float*)d_in[10];
    const float* b_dec = (const float*)d_in[11];
    const float* W1    = (const float*)d_in[12];
    const float* b1    = (const float*)d_in[13];
    const float* W2    = (const float*)d_in[14];
    const float* b2    = (const float*)d_in[15];
    const float* beta  = (const float*)d_in[16];
    const float* fw    = (const float*)d_in[17];
    const float* fb    = (const float*)d_in[18];
    const float* fs    = (const float*)d_in[19];

    float* ws      = (float*)d_ws;
    float* accums  = ws + OFF_ACC;
    float* rdeg    = ws + OFF_RDEG;
    float* vm_ws   = ws + OFF_VM;
    float* vv_ws   = ws + OFF_VV;
    float* zs_ws   = ws + OFF_ZS;
    float* zss_ws  = ws + OFF_ZSS;
    float* klp     = ws + OFF_KLP;
    float* msep    = ws + OFF_MSEP;
    float* xhg     = ws + OFF_XHG;
    unsigned short* h_ws = (unsigned short*)(ws + OFF_H);
    unsigned short* gsb  = (unsigned short*)(ws + OFF_GSB);
    float* out = (float*)d_out;

    bool big = ws_size >= WS_NEED;

    k_deg<<<ROWS / 4, 256, 0, stream>>>(gs, rdeg, accums, big ? gsb : nullptr);
    if (big) {
        k_hwgemm<true><<<2 * BB, 1024, 0, stream>>>(gs, gsb, hs, W_s, b_s, W_mu, W_lv,
                                                    rdeg, h_ws, vm_ws, vv_ws);
        k_muflow<true><<<4 * BB, 512, 0, stream>>>(gs, gsb, vm_ws, vv_ws, eps, b_mu, b_lv,
                                                   beta, fw, fb, fs, rdeg, zs_ws, zss_ws,
                                                   klp);
        k_dec<true><<<4 * BB, 512, 0, stream>>>(gs, gsb, zss_ws, zs_ws, h_ws, W_dec, b_dec,
                                                msep, xhg);
    } else {
        k_hwgemm<false><<<2 * BB, 1024, 0, stream>>>(gs, gsb, hs, W_s, b_s, W_mu, W_lv,
                                                     rdeg, h_ws, vm_ws, vv_ws);
        k_muflow<false><<<4 * BB, 512, 0, stream>>>(gs, gsb, vm_ws, vv_ws, eps, b_mu, b_lv,
                                                    beta, fw, fb, fs, rdeg, zs_ws, zss_ws,
                                                    klp);
        k_dec<false><<<4 * BB, 512, 0, stream>>>(gs, gsb, zss_ws, zs_ws, h_ws, W_dec, b_dec,
                                                 msep, xhg);
    }
    k_cls<<<BB, 64, 0, stream>>>(xhg, klp, msep, W1, b1, W2, b2, labels, accums, out);
}